// Round 5
// baseline (614.307 us; speedup 1.0000x reference)
//
#include <hip/hip_runtime.h>
#include <stdint.h>

#define DEVI __device__ __forceinline__

typedef __attribute__((ext_vector_type(4))) float f32x4;
typedef __attribute__((ext_vector_type(8))) short bf16x8;
typedef __attribute__((ext_vector_type(4))) unsigned short u16x4;

DEVI unsigned short f2bf(float x) {
  union { float f; uint32_t u; } v; v.f = x;
  uint32_t r = v.u + 0x7FFFu + ((v.u >> 16) & 1u);  // RNE
  return (unsigned short)(r >> 16);
}
DEVI float bf2f(unsigned short h) {
  union { uint32_t u; float f; } v; v.u = ((uint32_t)h) << 16;
  return v.f;
}

DEVI void async16(const void* g, void* l) {
  __builtin_amdgcn_global_load_lds((__attribute__((address_space(1))) void*)g,
                                   (__attribute__((address_space(3))) void*)l,
                                   16, 0, 0);
}

// ---------------- P0: fp32 -> bf16 hi/lo split (a1 & a2 in one launch) -------
__global__ void k_split2(const float* __restrict__ x0, unsigned short* __restrict__ h0,
                         unsigned short* __restrict__ l0,
                         const float* __restrict__ x1, unsigned short* __restrict__ h1,
                         unsigned short* __restrict__ l1) {
  const long i = (long)blockIdx.x * 256 + threadIdx.x;
  const float* x = blockIdx.y ? x1 : x0;
  unsigned short* hh = blockIdx.y ? h1 : h0;
  unsigned short* ll = blockIdx.y ? l1 : l0;
  const f32x4 v = ((const f32x4*)x)[i];
  u16x4 H, L;
#pragma unroll
  for (int j = 0; j < 4; ++j) {
    H[j] = f2bf(v[j]);
    L[j] = f2bf(v[j] - bf2f(H[j]));
  }
  ((u16x4*)hh)[i] = H;
  ((u16x4*)ll)[i] = L;
}

__global__ void k_split(const float* __restrict__ x, unsigned short* __restrict__ hi,
                        unsigned short* __restrict__ lo, const long n4) {
  const long i = (long)blockIdx.x * 256 + threadIdx.x;
  if (i >= n4) return;
  const f32x4 v = ((const f32x4*)x)[i];
  u16x4 H, L;
#pragma unroll
  for (int j = 0; j < 4; ++j) {
    H[j] = f2bf(v[j]);
    L[j] = f2bf(v[j] - bf2f(H[j]));
  }
  ((u16x4*)hi)[i] = H;
  ((u16x4*)lo)[i] = L;
}

// ---------------- GEMM: C = A * B^T, 256x256 tile, 8 waves, 8-phase ----------
// Deep pipeline, 160 KiB LDS:
//   A: 3-parity ring (3 x 2 planes x 16 KiB = 96 KiB), read parity i%3,
//      stage A(i+2) into (i+2)%3 during phases 0-1 -> 7-8 phases of lead.
//   B: 2-parity ring (2 x 2 planes = 64 KiB), B-frags bunch-read in phase 0,
//      stage B(i+2) into the just-read parity during phases 2-3.
// Gate: single counted vmcnt(8) at end of ph3 -> waits only for loads issued
// in iter i-1 (>= 4 phases old), leaves all 8 of this iter's loads in flight.
//   SPLIT:  planes = {Ah, Al, Bh, Bl}, KSTEP=32 (hi/lo split, 3 MFMA/frag-pair)
//   !SPLIT: planes = {A(k0:31), A(k32:63), B(k0:31), B(k32:63)}, KSTEP=64
// Plane layout: row-major [256 rows][4 chunks x 8 ushort], chunk position
// swizzled c' = kc ^ ((row>>1)&3) (both-sides swizzle: pre-swizzled GLOBAL
// source + swizzled ds_read index; global_load_lds dest stays linear).
// Staging map: thread t -> row t>>2, chunk t&3 => 4 lanes read one contiguous
// 64B row segment (fully-used cache lines).
template<bool SPLIT, bool OUTSPLIT, bool DUAL>
__global__ __launch_bounds__(512, 2)
void k_gemm256(const unsigned short* __restrict__ Ah, const unsigned short* __restrict__ Al,
               const unsigned short* __restrict__ Bh, const unsigned short* __restrict__ Bl,
               const float* __restrict__ bias,
               float* __restrict__ Cf, unsigned short* __restrict__ Ch,
               unsigned short* __restrict__ Cl,
               const unsigned short* __restrict__ Ax, const unsigned short* __restrict__ Bx,
               float* __restrict__ Cx,
               const int Kd, const int Nn,
               const long sA, const long sB, const long sC,
               const int lgx, const int lgy) {
  __shared__ __align__(16) unsigned short smem[81920];  // 160 KiB
  const int tid  = threadIdx.x;
  const int lane = tid & 63;
  const int wave = tid >> 6;
  const int wm = wave >> 2, wn = wave & 3;   // 2x4 wave grid, wave tile 128x64
  const int m16 = lane & 15, quad = lane >> 4;

  // bijective XCD-chunked swizzle: same-XCD consecutive blocks sweep `by`
  const int nper = (int)gridDim.x >> 3;
  const int lin = (int)blockIdx.x;
  const int wg = (lin & 7) * nper + (lin >> 3);
  const int by = wg & ((1 << lgy) - 1);
  const int bx = (wg >> lgy) & ((1 << lgx) - 1);
  int bz = wg >> (lgx + lgy);

  const unsigned short* Ap = Ah;
  const unsigned short* Bp = Bh;
  float* Cp = Cf;
  if (DUAL && bz >= 16) { Ap = Ax; Bp = Bx; Cp = Cx; bz -= 16; }

  const long aTile = (long)bz * sA + (long)bx * 256 * Kd;
  const long bTile = (long)bz * sB + (long)by * 256 * Kd;

  // staging map: thread t covers (row = t>>2, chunk kc = (t&3) ^ ((row>>1)&3))
  // loads 0/1 cover rows row0 and row0+128 (same kc: (row+128)>>1 ≡ row>>1 mod 4)
  const int row0 = tid >> 2;                       // 0..127
  const int kc   = (tid & 3) ^ ((row0 >> 1) & 3);  // pre-swizzled global chunk
  const long rstep = 128L * Kd;
  const long aoff = aTile + (long)row0 * Kd + kc * 8;
  const long boff = bTile + (long)row0 * Kd + kc * 8;

  const unsigned short* gA0 = Ap + aoff;
  const unsigned short* gA1 = SPLIT ? (Al + aoff) : (Ap + aoff + 32);
  const unsigned short* gB0 = Bp + boff;
  const unsigned short* gB1 = SPLIT ? (Bl + boff) : (Bp + boff + 32);

  // wave-uniform LDS staging base within a plane (ushort units)
  const int ldsW = wave * 512;

  f32x4 acc[8][4];
#pragma unroll
  for (int i = 0; i < 8; ++i)
#pragma unroll
    for (int j = 0; j < 4; ++j) acc[i][j] = (f32x4){0.0f, 0.0f, 0.0f, 0.0f};

  const int KSTEP = SPLIT ? 32 : 64;
  const int NT = Kd / KSTEP;

  // LDS map (ushort units): A parity p at p*16384 (A0) / +8192 (A1), p=0..2
  //                         B parity q at 49152 + q*16384 (B0) / +8192 (B1)
  // prologue (age order): A(0), B(0), A(1), B(1); gate vmcnt(8) = A(0),B(0)
  async16(gA0,                 smem + ldsW);
  async16(gA0 + rstep,         smem + ldsW + 4096);
  async16(gA1,                 smem + 8192 + ldsW);
  async16(gA1 + rstep,         smem + 8192 + ldsW + 4096);
  async16(gB0,                 smem + 49152 + ldsW);
  async16(gB0 + rstep,         smem + 49152 + ldsW + 4096);
  async16(gB1,                 smem + 49152 + 8192 + ldsW);
  async16(gB1 + rstep,         smem + 49152 + 8192 + ldsW + 4096);
  async16(gA0 + KSTEP,         smem + 16384 + ldsW);
  async16(gA0 + KSTEP + rstep, smem + 16384 + ldsW + 4096);
  async16(gA1 + KSTEP,         smem + 16384 + 8192 + ldsW);
  async16(gA1 + KSTEP + rstep, smem + 16384 + 8192 + ldsW + 4096);
  async16(gB0 + KSTEP,         smem + 49152 + 16384 + ldsW);
  async16(gB0 + KSTEP + rstep, smem + 49152 + 16384 + ldsW + 4096);
  async16(gB1 + KSTEP,         smem + 49152 + 16384 + 8192 + ldsW);
  async16(gB1 + KSTEP + rstep, smem + 49152 + 16384 + 8192 + ldsW + 4096);
  asm volatile("s_waitcnt vmcnt(8)" ::: "memory");
  asm volatile("s_barrier" ::: "memory");

  // fragment read index: element (row, c') at bf16x8 idx row*4 + c',
  // c' = quad ^ kx with kx = (m16>>1)&3
  const int kx   = (m16 >> 1) & 3;
  const int cp   = quad ^ kx;
  const int aidx = (wm * 128 + m16) * 4 + cp;
  const int bidx = (wn * 64  + m16) * 4 + cp;

#define MFMA_PHASE(q, A0, A1)                                                               \
  {                                                                                         \
    _Pragma("unroll")                                                                       \
    for (int j = 0; j < 2; ++j) {                                                           \
      _Pragma("unroll")                                                                     \
      for (int tn = 0; tn < 4; ++tn) {                                                      \
        acc[2*(q)+j][tn] = __builtin_amdgcn_mfma_f32_16x16x32_bf16(A0[j], b0[tn],           \
                                                                   acc[2*(q)+j][tn], 0,0,0);\
        if (SPLIT) {                                                                        \
          acc[2*(q)+j][tn] = __builtin_amdgcn_mfma_f32_16x16x32_bf16(A0[j], b1[tn],         \
                                                                   acc[2*(q)+j][tn], 0,0,0);\
          acc[2*(q)+j][tn] = __builtin_amdgcn_mfma_f32_16x16x32_bf16(A1[j], b0[tn],         \
                                                                   acc[2*(q)+j][tn], 0,0,0);\
        } else {                                                                            \
          acc[2*(q)+j][tn] = __builtin_amdgcn_mfma_f32_16x16x32_bf16(A1[j], b1[tn],         \
                                                                   acc[2*(q)+j][tn], 0,0,0);\
        }                                                                                   \
      }                                                                                     \
    }                                                                                       \
  }

  int aRd = 0;  // A read-parity base: 0, 16384, 32768 rotating
  for (int i = 0; i < NT; ++i) {
    const int aSt = (aRd == 0) ? 32768 : aRd - 16384;   // (parity+2)%3 base
    const int bB  = 49152 + ((i & 1) << 14);            // B parity base
    const bf16x8* fA0 = (const bf16x8*)(smem + aRd);
    const bf16x8* fA1 = (const bf16x8*)(smem + aRd + 8192);
    const bf16x8* fB0 = (const bf16x8*)(smem + bB);
    const bf16x8* fB1 = (const bf16x8*)(smem + bB + 8192);
    const int kN = (i + 2) * KSTEP;
    const bool st = (i + 2 < NT);

    bf16x8 b0[4], b1[4];
    // ---------------- phase 0: B-frags + A tm{0,1} | stage A0(i+2) ----------
    {
#pragma unroll
      for (int tn = 0; tn < 4; ++tn) {
        b0[tn] = fB0[bidx + tn * 64];
        b1[tn] = fB1[bidx + tn * 64];
      }
      bf16x8 a0[2], a1[2];
      a0[0] = fA0[aidx];      a0[1] = fA0[aidx + 64];
      a1[0] = fA1[aidx];      a1[1] = fA1[aidx + 64];
      if (st) {
        async16(gA0 + kN,         smem + aSt + ldsW);
        async16(gA0 + kN + rstep, smem + aSt + ldsW + 4096);
      }
      asm volatile("s_waitcnt lgkmcnt(8)" ::: "memory");
      asm volatile("s_barrier" ::: "memory");
      asm volatile("s_waitcnt lgkmcnt(0)" ::: "memory");
      __builtin_amdgcn_sched_barrier(0);
      __builtin_amdgcn_s_setprio(1);
      MFMA_PHASE(0, a0, a1);
      __builtin_amdgcn_s_setprio(0);
      asm volatile("s_barrier" ::: "memory");
    }
    // ---------------- phase 1: A tm{2,3} | stage A1(i+2) --------------------
    {
      bf16x8 a0[2], a1[2];
      a0[0] = fA0[aidx + 128]; a0[1] = fA0[aidx + 192];
      a1[0] = fA1[aidx + 128]; a1[1] = fA1[aidx + 192];
      if (st) {
        async16(gA1 + kN,         smem + aSt + 8192 + ldsW);
        async16(gA1 + kN + rstep, smem + aSt + 8192 + ldsW + 4096);
      }
      asm volatile("s_barrier" ::: "memory");
      asm volatile("s_waitcnt lgkmcnt(0)" ::: "memory");
      __builtin_amdgcn_sched_barrier(0);
      __builtin_amdgcn_s_setprio(1);
      MFMA_PHASE(1, a0, a1);
      __builtin_amdgcn_s_setprio(0);
      asm volatile("s_barrier" ::: "memory");
    }
    // ---------------- phase 2: A tm{4,5} | stage B0(i+2) --------------------
    {
      bf16x8 a0[2], a1[2];
      a0[0] = fA0[aidx + 256]; a0[1] = fA0[aidx + 320];
      a1[0] = fA1[aidx + 256]; a1[1] = fA1[aidx + 320];
      if (st) {
        async16(gB0 + kN,         smem + bB + ldsW);
        async16(gB0 + kN + rstep, smem + bB + ldsW + 4096);
      }
      asm volatile("s_barrier" ::: "memory");
      asm volatile("s_waitcnt lgkmcnt(0)" ::: "memory");
      __builtin_amdgcn_sched_barrier(0);
      __builtin_amdgcn_s_setprio(1);
      MFMA_PHASE(2, a0, a1);
      __builtin_amdgcn_s_setprio(0);
      asm volatile("s_barrier" ::: "memory");
    }
    // ---------------- phase 3: A tm{6,7} | stage B1(i+2) | vmcnt gate -------
    {
      bf16x8 a0[2], a1[2];
      a0[0] = fA0[aidx + 384]; a0[1] = fA0[aidx + 448];
      a1[0] = fA1[aidx + 384]; a1[1] = fA1[aidx + 448];
      if (st) {
        async16(gB1 + kN,         smem + bB + 8192 + ldsW);
        async16(gB1 + kN + rstep, smem + bB + 8192 + ldsW + 4096);
      }
      asm volatile("s_barrier" ::: "memory");
      asm volatile("s_waitcnt lgkmcnt(0)" ::: "memory");
      __builtin_amdgcn_sched_barrier(0);
      __builtin_amdgcn_s_setprio(1);
      MFMA_PHASE(3, a0, a1);
      __builtin_amdgcn_s_setprio(0);
      if (st) asm volatile("s_waitcnt vmcnt(8)" ::: "memory");
      else    asm volatile("s_waitcnt vmcnt(0)" ::: "memory");
      asm volatile("s_barrier" ::: "memory");
    }
    aRd = (aRd == 32768) ? 0 : aRd + 16384;
  }
#undef MFMA_PHASE

  // epilogue: C/D layout col=lane&15, row=quad*4+i (m89/m91-verified)
  const long crow0 = (long)bx * 256 + wm * 128;
  const long ccol0 = (long)by * 256 + wn * 64;
  const long cBase = (long)bz * sC;
#pragma unroll
  for (int tn = 0; tn < 4; ++tn) {
    const long gcol = ccol0 + tn * 16 + m16;
    const float bv = OUTSPLIT ? bias[gcol] : 0.0f;
#pragma unroll
    for (int tm = 0; tm < 8; ++tm) {
#pragma unroll
      for (int r = 0; r < 4; ++r) {
        const long grow = crow0 + tm * 16 + quad * 4 + r;
        const long idx = cBase + grow * (long)Nn + gcol;
        const float val = acc[tm][tn][r] + bv;
        if (OUTSPLIT) {
          unsigned short h = f2bf(val);
          Ch[idx] = h;
          Cl[idx] = f2bf(val - bf2f(h));
        } else {
          Cp[idx] = val;
        }
      }
    }
  }
}

// ---------------- P3+P4a fused: row stats & column partial stats -------------
__global__ void k_rcstats(const float* __restrict__ S, float* __restrict__ m1,
                          float* __restrict__ r1, float* __restrict__ mp,
                          float* __restrict__ sp) {
  if (blockIdx.x < 4096) {
    // per-row (over k) max & 1/sumexp; one wave per row
    const int lane = threadIdx.x & 63;
    const int wave = threadIdx.x >> 6;
    const long row = (long)blockIdx.x * 4 + wave;
    const f32x4* p = (const f32x4*)(S + (row << 10));
    f32x4 v[4];
#pragma unroll
    for (int j = 0; j < 4; ++j) v[j] = p[lane + j * 64];
    float mx = -3.4e38f;
#pragma unroll
    for (int j = 0; j < 4; ++j)
#pragma unroll
      for (int c = 0; c < 4; ++c) mx = fmaxf(mx, v[j][c]);
#pragma unroll
    for (int off = 32; off > 0; off >>= 1) mx = fmaxf(mx, __shfl_xor(mx, off, 64));
    float s = 0.0f;
#pragma unroll
    for (int j = 0; j < 4; ++j)
#pragma unroll
      for (int c = 0; c < 4; ++c) s += __expf(v[j][c] - mx);
#pragma unroll
    for (int off = 32; off > 0; off >>= 1) s += __shfl_xor(s, off, 64);
    if (lane == 0) { m1[row] = mx; r1[row] = 1.0f / s; }
  } else {
    // per-column (over l) partial stats, 256-row strips
    const int b = blockIdx.x - 4096;
    const int kc = b & 3, lc = (b >> 2) & 3, n = b >> 4;
    const int k = kc * 256 + threadIdx.x;
    const float* p = S + ((long)n << 20) + ((long)(lc * 256) << 10) + k;
    float m = -3.4e38f, s = 0.0f;
    for (int i = 0; i < 256; ++i) {
      const float x = p[(long)i << 10];
      const float nm = fmaxf(m, x);
      s = s * __expf(m - nm) + __expf(x - nm);
      m = nm;
    }
    const long o = ((long)(n * 4 + lc) << 10) + k;
    mp[o] = m; sp[o] = s;
  }
}

__global__ void k_colstats_comb(const float* __restrict__ mp, const float* __restrict__ sp,
                                float* __restrict__ m2, float* __restrict__ r2) {
  const int n = blockIdx.y;
  const int k = blockIdx.x * 256 + threadIdx.x;
  float m = -3.4e38f, s = 0.0f;
#pragma unroll
  for (int c = 0; c < 4; ++c) {
    const long o = ((long)(n * 4 + c) << 10) + k;
    const float mc = mp[o], sc = sp[o];
    const float nm = fmaxf(m, mc);
    s = s * __expf(m - nm) + sc * __expf(mc - nm);
    m = nm;
  }
  m2[((long)n << 10) + k] = m;
  r2[((long)n << 10) + k] = 1.0f / s;
}

// ---------------- P5: A1 = softmax_k(S) bf16 ; A2T = softmax_l(S)^T bf16 -----
__global__ void k_agen(const float* __restrict__ S, const float* __restrict__ m1,
                       const float* __restrict__ r1, const float* __restrict__ m2,
                       const float* __restrict__ r2, unsigned short* __restrict__ A1,
                       unsigned short* __restrict__ A2T) {
  __shared__ float e2[64][65];
  const int n = blockIdx.z;
  const int k0 = blockIdx.x * 64, l0 = blockIdx.y * 64;
  const int q = threadIdx.x >> 4, p = threadIdx.x & 15;
  const long nb = (long)n << 20;
  const int kk = k0 + p * 4;
  const f32x4 mm2 = *(const f32x4*)(m2 + ((long)n << 10) + kk);
  const f32x4 rr2 = *(const f32x4*)(r2 + ((long)n << 10) + kk);
#pragma unroll
  for (int rr = 0; rr < 4; ++rr) {
    const int lrow = rr * 16 + q;
    const int l = l0 + lrow;
    const f32x4 s4 = *(const f32x4*)(S + nb + ((long)l << 10) + kk);
    const float mv = m1[((long)n << 10) + l], rv = r1[((long)n << 10) + l];
    u16x4 o;
#pragma unroll
    for (int j = 0; j < 4; ++j) {
      o[j] = f2bf(__expf(s4[j] - mv) * rv);
      e2[lrow][p * 4 + j] = __expf(s4[j] - mm2[j]) * rr2[j];
    }
    *(u16x4*)(A1 + nb + ((long)l << 10) + kk) = o;
  }
  __syncthreads();
#pragma unroll
  for (int rr = 0; rr < 4; ++rr) {
    const int krow = rr * 16 + q;
    u16x4 o;
#pragma unroll
    for (int j = 0; j < 4; ++j) o[j] = f2bf(e2[p * 4 + j][krow]);
    *(u16x4*)(A2T + nb + ((long)(k0 + krow) << 10) + (l0 + p * 4)) = o;
  }
}

// ---------------- transpose fp32 [n][r][c] -> bf16 [n][c][r], both inputs ----
__global__ void k_transpose2(const float* __restrict__ in0, unsigned short* __restrict__ out0,
                             const float* __restrict__ in1, unsigned short* __restrict__ out1) {
  __shared__ float t[64][65];
  const int zz = blockIdx.z;
  const int n = zz & 15;
  const float* in = (zz < 16) ? in0 : in1;
  unsigned short* out = (zz < 16) ? out0 : out1;
  const int c0 = blockIdx.x * 64, r0 = blockIdx.y * 64;
  const int q = threadIdx.x >> 4, p = threadIdx.x & 15;
  const long nb = (long)n << 20;
#pragma unroll
  for (int rr = 0; rr < 4; ++rr) {
    const int r = rr * 16 + q;
    const f32x4 v = *(const f32x4*)(in + nb + ((long)(r0 + r) << 10) + c0 + p * 4);
#pragma unroll
    for (int j = 0; j < 4; ++j) t[r][p * 4 + j] = v[j];
  }
  __syncthreads();
#pragma unroll
  for (int rr = 0; rr < 4; ++rr) {
    const int c = rr * 16 + q;
    u16x4 o;
#pragma unroll
    for (int j = 0; j < 4; ++j) o[j] = f2bf(t[p * 4 + j][c]);
    *(u16x4*)(out + nb + ((long)(c0 + c) << 10) + (r0 + p * 4)) = o;
  }
}

extern "C" void kernel_launch(void* const* d_in, const int* in_sizes, int n_in,
                              void* d_out, int out_size, void* d_ws, size_t ws_size,
                              hipStream_t stream) {
  const float* a1 = (const float*)d_in[0];
  const float* a2 = (const float*)d_in[1];
  const float* Gw = (const float*)d_in[2];
  const float* Gb = (const float*)d_in[3];
  float* out = (float*)d_out;
  char* ws = (char*)d_ws;
  const size_t MB = 1ull << 20;

  // phase-1 regions
  unsigned short* a1h  = (unsigned short*)(ws + 0 * MB);
  unsigned short* a1l  = (unsigned short*)(ws + 32 * MB);
  unsigned short* a2h  = (unsigned short*)(ws + 64 * MB);
  unsigned short* a2l  = (unsigned short*)(ws + 96 * MB);
  unsigned short* a2ph = (unsigned short*)(ws + 128 * MB);
  unsigned short* a2pl = (unsigned short*)(ws + 160 * MB);
  unsigned short* Gh   = (unsigned short*)(ws + 192 * MB);
  unsigned short* Gl   = (unsigned short*)(ws + 194 * MB);
  char* st = ws + 196 * MB;
  float* m1 = (float*)(st);
  float* r1 = (float*)(st + 64 * 1024);
  float* m2 = (float*)(st + 128 * 1024);
  float* r2 = (float*)(st + 192 * 1024);
  float* mp = (float*)(st + 256 * 1024);
  float* sp = (float*)(st + 512 * 1024);
  // lifetime-reused regions
  float* S            = (float*)(ws + 64 * MB);           // over a2h/a2l (dead after P1)
  unsigned short* A1  = (unsigned short*)(ws + 0 * MB);   // over a1h (dead after P2)
  unsigned short* A2T = (unsigned short*)(ws + 32 * MB);  // over a1l
  unsigned short* a2T = (unsigned short*)(ws + 128 * MB); // over a2ph (dead after P2)
  unsigned short* a1T = (unsigned short*)(ws + 160 * MB); // over a2pl

  const long B1M = 1048576;

  // P0: hi/lo splits (a1 & a2 fused; G separate)
  k_split2<<<dim3(16384, 2), 256, 0, stream>>>(a1, a1h, a1l, a2, a2h, a2l);
  k_split<<<1024, 256, 0, stream>>>(Gw, Gh, Gl, 262144);

  // P1: a2p[m][e] = a2[m][:] . Gw[e][:] + Gb[e]   (M=16384 -> 64x4 tiles)
  k_gemm256<true, true, false><<<256, 512, 0, stream>>>(
      a2h, a2l, Gh, Gl, Gb, nullptr, a2ph, a2pl, nullptr, nullptr, nullptr,
      1024, 1024, 0, 0, 0, 6, 2);

  // P2: S[n][l][k] = a1[n][l][:] . a2p[n][k][:]   (fp32 out, 4x4x16 tiles)
  k_gemm256<true, false, false><<<256, 512, 0, stream>>>(
      a1h, a1l, a2ph, a2pl, nullptr, S, nullptr, nullptr, nullptr, nullptr, nullptr,
      1024, 1024, B1M, B1M, B1M, 2, 2);

  // P3+P4a fused: row stats + col partial stats (one S read each)
  k_rcstats<<<4352, 256, 0, stream>>>(S, m1, r1, mp, sp);
  k_colstats_comb<<<dim3(4, 16), 256, 0, stream>>>(mp, sp, m2, r2);

  // P5: A1 (softmax over k) and A2T (softmax over l, transposed) in bf16
  k_agen<<<dim3(16, 16, 16), 256, 0, stream>>>(S, m1, r1, m2, r2, A1, A2T);

  // bf16 transposes of the raw inputs (both in one launch)
  k_transpose2<<<dim3(16, 16, 32), 256, 0, stream>>>(a2, a2T, a1, a1T);

  // P6+P7 merged: z<16 -> M1 = A1 . a2T^T ; z>=16 -> M2 = A2T . a1T^T
  k_gemm256<false, false, true><<<512, 512, 0, stream>>>(
      A1, nullptr, a2T, nullptr, nullptr, out, nullptr, nullptr,
      A2T, a1T, out + 16777216,
      1024, 1024, B1M, B1M, B1M, 2, 2);
}

// Round 6
// 596.435 us; speedup vs baseline: 1.0300x; 1.0300x over previous
//
#include <hip/hip_runtime.h>
#include <stdint.h>

#define DEVI __device__ __forceinline__

typedef __attribute__((ext_vector_type(4))) float f32x4;
typedef __attribute__((ext_vector_type(8))) short bf16x8;
typedef __attribute__((ext_vector_type(4))) unsigned short u16x4;

DEVI unsigned short f2bf(float x) {
  union { float f; uint32_t u; } v; v.f = x;
  uint32_t r = v.u + 0x7FFFu + ((v.u >> 16) & 1u);  // RNE
  return (unsigned short)(r >> 16);
}
DEVI float bf2f(unsigned short h) {
  union { uint32_t u; float f; } v; v.u = ((uint32_t)h) << 16;
  return v.f;
}

DEVI void async16(const void* g, void* l) {
  __builtin_amdgcn_global_load_lds((__attribute__((address_space(1))) void*)g,
                                   (__attribute__((address_space(3))) void*)l,
                                   16, 0, 0);
}

// ---------------- P0: fp32 -> bf16 hi/lo split (a1 & a2 in one launch) -------
__global__ void k_split2(const float* __restrict__ x0, unsigned short* __restrict__ h0,
                         unsigned short* __restrict__ l0,
                         const float* __restrict__ x1, unsigned short* __restrict__ h1,
                         unsigned short* __restrict__ l1) {
  const long i = (long)blockIdx.x * 256 + threadIdx.x;
  const float* x = blockIdx.y ? x1 : x0;
  unsigned short* hh = blockIdx.y ? h1 : h0;
  unsigned short* ll = blockIdx.y ? l1 : l0;
  const f32x4 v = ((const f32x4*)x)[i];
  u16x4 H, L;
#pragma unroll
  for (int j = 0; j < 4; ++j) {
    H[j] = f2bf(v[j]);
    L[j] = f2bf(v[j] - bf2f(H[j]));
  }
  ((u16x4*)hh)[i] = H;
  ((u16x4*)ll)[i] = L;
}

__global__ void k_split(const float* __restrict__ x, unsigned short* __restrict__ hi,
                        unsigned short* __restrict__ lo, const long n4) {
  const long i = (long)blockIdx.x * 256 + threadIdx.x;
  if (i >= n4) return;
  const f32x4 v = ((const f32x4*)x)[i];
  u16x4 H, L;
#pragma unroll
  for (int j = 0; j < 4; ++j) {
    H[j] = f2bf(v[j]);
    L[j] = f2bf(v[j] - bf2f(H[j]));
  }
  ((u16x4*)hi)[i] = H;
  ((u16x4*)lo)[i] = L;
}

// ---------------- GEMM: C = A * B^T, 256x256 tile, 8 waves, 8-phase ----------
// Deep pipeline, 160 KiB LDS:
//   A: 3-parity ring (3 x 2 planes x 16 KiB = 96 KiB), read parity i%3,
//      stage A(i+2) into (i+2)%3 during phases 0-1.
//   B: 2-parity ring (2 x 2 planes = 64 KiB), B-frags bunch-read in phase 0,
//      stage B(i+2) into the just-read parity during phases 2-3.
// ONE barrier per phase (end barrier only; r6 change): lgkmcnt is per-wave, so
// a wave's MFMA needs only its OWN ds_reads; all LDS reuse hazards (B parity
// at i+2, A parity at i+3) are separated by >=1 end-of-phase barrier. Without
// the mid-phase barrier the 2 waves/SIMD de-skew: one wave's ds_read latency
// hides under the sibling's MFMA (setprio arbitrates in favor of MFMA).
// Gate: single counted vmcnt(8) at end of ph3 -> waits only for loads issued
// in iter i-1, leaves all 8 of this iter's loads in flight.
//   SPLIT:  planes = {Ah, Al, Bh, Bl}, KSTEP=32 (hi/lo split, 3 MFMA/frag-pair)
//   !SPLIT: planes = {A(k0:31), A(k32:63), B(k0:31), B(k32:63)}, KSTEP=64
// Plane layout: row-major [256 rows][4 chunks x 8 ushort], chunk position
// swizzled c' = kc ^ ((row>>1)&3) (both-sides swizzle: pre-swizzled GLOBAL
// source + swizzled ds_read index; global_load_lds dest stays linear).
// Staging map: thread t -> row t>>2, chunk t&3 => 4 lanes read one contiguous
// 64B row segment (fully-used cache lines).
template<bool SPLIT, bool OUTSPLIT, bool DUAL>
__global__ __launch_bounds__(512, 2)
void k_gemm256(const unsigned short* __restrict__ Ah, const unsigned short* __restrict__ Al,
               const unsigned short* __restrict__ Bh, const unsigned short* __restrict__ Bl,
               const float* __restrict__ bias,
               float* __restrict__ Cf, unsigned short* __restrict__ Ch,
               unsigned short* __restrict__ Cl,
               const unsigned short* __restrict__ Ax, const unsigned short* __restrict__ Bx,
               float* __restrict__ Cx,
               const int Kd, const int Nn,
               const long sA, const long sB, const long sC,
               const int lgx, const int lgy) {
  __shared__ __align__(16) unsigned short smem[81920];  // 160 KiB
  const int tid  = threadIdx.x;
  const int lane = tid & 63;
  const int wave = tid >> 6;
  const int wm = wave >> 2, wn = wave & 3;   // 2x4 wave grid, wave tile 128x64
  const int m16 = lane & 15, quad = lane >> 4;

  // bijective XCD-chunked swizzle: same-XCD consecutive blocks sweep `by`
  const int nper = (int)gridDim.x >> 3;
  const int lin = (int)blockIdx.x;
  const int wg = (lin & 7) * nper + (lin >> 3);
  const int by = wg & ((1 << lgy) - 1);
  const int bx = (wg >> lgy) & ((1 << lgx) - 1);
  int bz = wg >> (lgx + lgy);

  const unsigned short* Ap = Ah;
  const unsigned short* Bp = Bh;
  float* Cp = Cf;
  if (DUAL && bz >= 16) { Ap = Ax; Bp = Bx; Cp = Cx; bz -= 16; }

  const long aTile = (long)bz * sA + (long)bx * 256 * Kd;
  const long bTile = (long)bz * sB + (long)by * 256 * Kd;

  // staging map: thread t covers (row = t>>2, chunk kc = (t&3) ^ ((row>>1)&3))
  // loads 0/1 cover rows row0 and row0+128 (same kc: (row+128)>>1 ≡ row>>1 mod 4)
  const int row0 = tid >> 2;                       // 0..127
  const int kc   = (tid & 3) ^ ((row0 >> 1) & 3);  // pre-swizzled global chunk
  const long rstep = 128L * Kd;
  const long aoff = aTile + (long)row0 * Kd + kc * 8;
  const long boff = bTile + (long)row0 * Kd + kc * 8;

  const unsigned short* gA0 = Ap + aoff;
  const unsigned short* gA1 = SPLIT ? (Al + aoff) : (Ap + aoff + 32);
  const unsigned short* gB0 = Bp + boff;
  const unsigned short* gB1 = SPLIT ? (Bl + boff) : (Bp + boff + 32);

  // wave-uniform LDS staging base within a plane (ushort units)
  const int ldsW = wave * 512;

  f32x4 acc[8][4];
#pragma unroll
  for (int i = 0; i < 8; ++i)
#pragma unroll
    for (int j = 0; j < 4; ++j) acc[i][j] = (f32x4){0.0f, 0.0f, 0.0f, 0.0f};

  const int KSTEP = SPLIT ? 32 : 64;
  const int NT = Kd / KSTEP;

  // LDS map (ushort units): A parity p at p*16384 (A0) / +8192 (A1), p=0..2
  //                         B parity q at 49152 + q*16384 (B0) / +8192 (B1)
  // prologue (age order): A(0), B(0), A(1), B(1); gate vmcnt(8) = A(0),B(0)
  async16(gA0,                 smem + ldsW);
  async16(gA0 + rstep,         smem + ldsW + 4096);
  async16(gA1,                 smem + 8192 + ldsW);
  async16(gA1 + rstep,         smem + 8192 + ldsW + 4096);
  async16(gB0,                 smem + 49152 + ldsW);
  async16(gB0 + rstep,         smem + 49152 + ldsW + 4096);
  async16(gB1,                 smem + 49152 + 8192 + ldsW);
  async16(gB1 + rstep,         smem + 49152 + 8192 + ldsW + 4096);
  async16(gA0 + KSTEP,         smem + 16384 + ldsW);
  async16(gA0 + KSTEP + rstep, smem + 16384 + ldsW + 4096);
  async16(gA1 + KSTEP,         smem + 16384 + 8192 + ldsW);
  async16(gA1 + KSTEP + rstep, smem + 16384 + 8192 + ldsW + 4096);
  async16(gB0 + KSTEP,         smem + 49152 + 16384 + ldsW);
  async16(gB0 + KSTEP + rstep, smem + 49152 + 16384 + ldsW + 4096);
  async16(gB1 + KSTEP,         smem + 49152 + 16384 + 8192 + ldsW);
  async16(gB1 + KSTEP + rstep, smem + 49152 + 16384 + 8192 + ldsW + 4096);
  asm volatile("s_waitcnt vmcnt(8)" ::: "memory");
  asm volatile("s_barrier" ::: "memory");

  // fragment read index: element (row, c') at bf16x8 idx row*4 + c',
  // c' = quad ^ kx with kx = (m16>>1)&3
  const int kx   = (m16 >> 1) & 3;
  const int cp   = quad ^ kx;
  const int aidx = (wm * 128 + m16) * 4 + cp;
  const int bidx = (wn * 64  + m16) * 4 + cp;

#define MFMA_PHASE(q, A0, A1)                                                               \
  {                                                                                         \
    _Pragma("unroll")                                                                       \
    for (int j = 0; j < 2; ++j) {                                                           \
      _Pragma("unroll")                                                                     \
      for (int tn = 0; tn < 4; ++tn) {                                                      \
        acc[2*(q)+j][tn] = __builtin_amdgcn_mfma_f32_16x16x32_bf16(A0[j], b0[tn],           \
                                                                   acc[2*(q)+j][tn], 0,0,0);\
        if (SPLIT) {                                                                        \
          acc[2*(q)+j][tn] = __builtin_amdgcn_mfma_f32_16x16x32_bf16(A0[j], b1[tn],         \
                                                                   acc[2*(q)+j][tn], 0,0,0);\
          acc[2*(q)+j][tn] = __builtin_amdgcn_mfma_f32_16x16x32_bf16(A1[j], b0[tn],         \
                                                                   acc[2*(q)+j][tn], 0,0,0);\
        } else {                                                                            \
          acc[2*(q)+j][tn] = __builtin_amdgcn_mfma_f32_16x16x32_bf16(A1[j], b1[tn],         \
                                                                   acc[2*(q)+j][tn], 0,0,0);\
        }                                                                                   \
      }                                                                                     \
    }                                                                                       \
  }

  int aRd = 0;  // A read-parity base: 0, 16384, 32768 rotating
  for (int i = 0; i < NT; ++i) {
    const int aSt = (aRd == 0) ? 32768 : aRd - 16384;   // (parity+2)%3 base
    const int bB  = 49152 + ((i & 1) << 14);            // B parity base
    const bf16x8* fA0 = (const bf16x8*)(smem + aRd);
    const bf16x8* fA1 = (const bf16x8*)(smem + aRd + 8192);
    const bf16x8* fB0 = (const bf16x8*)(smem + bB);
    const bf16x8* fB1 = (const bf16x8*)(smem + bB + 8192);
    const int kN = (i + 2) * KSTEP;
    const bool st = (i + 2 < NT);

    bf16x8 b0[4], b1[4];
    // ---------------- phase 0: B-frags + A tm{0,1} | stage A0(i+2) ----------
    {
#pragma unroll
      for (int tn = 0; tn < 4; ++tn) {
        b0[tn] = fB0[bidx + tn * 64];
        b1[tn] = fB1[bidx + tn * 64];
      }
      bf16x8 a0[2], a1[2];
      a0[0] = fA0[aidx];      a0[1] = fA0[aidx + 64];
      a1[0] = fA1[aidx];      a1[1] = fA1[aidx + 64];
      if (st) {
        async16(gA0 + kN,         smem + aSt + ldsW);
        async16(gA0 + kN + rstep, smem + aSt + ldsW + 4096);
      }
      asm volatile("s_waitcnt lgkmcnt(0)" ::: "memory");
      __builtin_amdgcn_sched_barrier(0);
      __builtin_amdgcn_s_setprio(1);
      MFMA_PHASE(0, a0, a1);
      __builtin_amdgcn_s_setprio(0);
      asm volatile("s_barrier" ::: "memory");
    }
    // ---------------- phase 1: A tm{2,3} | stage A1(i+2) --------------------
    {
      bf16x8 a0[2], a1[2];
      a0[0] = fA0[aidx + 128]; a0[1] = fA0[aidx + 192];
      a1[0] = fA1[aidx + 128]; a1[1] = fA1[aidx + 192];
      if (st) {
        async16(gA1 + kN,         smem + aSt + 8192 + ldsW);
        async16(gA1 + kN + rstep, smem + aSt + 8192 + ldsW + 4096);
      }
      asm volatile("s_waitcnt lgkmcnt(0)" ::: "memory");
      __builtin_amdgcn_sched_barrier(0);
      __builtin_amdgcn_s_setprio(1);
      MFMA_PHASE(1, a0, a1);
      __builtin_amdgcn_s_setprio(0);
      asm volatile("s_barrier" ::: "memory");
    }
    // ---------------- phase 2: A tm{4,5} | stage B0(i+2) --------------------
    {
      bf16x8 a0[2], a1[2];
      a0[0] = fA0[aidx + 256]; a0[1] = fA0[aidx + 320];
      a1[0] = fA1[aidx + 256]; a1[1] = fA1[aidx + 320];
      if (st) {
        async16(gB0 + kN,         smem + bB + ldsW);
        async16(gB0 + kN + rstep, smem + bB + ldsW + 4096);
      }
      asm volatile("s_waitcnt lgkmcnt(0)" ::: "memory");
      __builtin_amdgcn_sched_barrier(0);
      __builtin_amdgcn_s_setprio(1);
      MFMA_PHASE(2, a0, a1);
      __builtin_amdgcn_s_setprio(0);
      asm volatile("s_barrier" ::: "memory");
    }
    // ---------------- phase 3: A tm{6,7} | stage B1(i+2) | vmcnt gate -------
    {
      bf16x8 a0[2], a1[2];
      a0[0] = fA0[aidx + 384]; a0[1] = fA0[aidx + 448];
      a1[0] = fA1[aidx + 384]; a1[1] = fA1[aidx + 448];
      if (st) {
        async16(gB1 + kN,         smem + bB + 8192 + ldsW);
        async16(gB1 + kN + rstep, smem + bB + 8192 + ldsW + 4096);
      }
      asm volatile("s_waitcnt lgkmcnt(0)" ::: "memory");
      __builtin_amdgcn_sched_barrier(0);
      __builtin_amdgcn_s_setprio(1);
      MFMA_PHASE(3, a0, a1);
      __builtin_amdgcn_s_setprio(0);
      if (st) asm volatile("s_waitcnt vmcnt(8)" ::: "memory");
      else    asm volatile("s_waitcnt vmcnt(0)" ::: "memory");
      asm volatile("s_barrier" ::: "memory");
    }
    aRd = (aRd == 32768) ? 0 : aRd + 16384;
  }
#undef MFMA_PHASE

  // epilogue: C/D layout col=lane&15, row=quad*4+i (m89/m91-verified)
  const long crow0 = (long)bx * 256 + wm * 128;
  const long ccol0 = (long)by * 256 + wn * 64;
  const long cBase = (long)bz * sC;
#pragma unroll
  for (int tn = 0; tn < 4; ++tn) {
    const long gcol = ccol0 + tn * 16 + m16;
    const float bv = OUTSPLIT ? bias[gcol] : 0.0f;
#pragma unroll
    for (int tm = 0; tm < 8; ++tm) {
#pragma unroll
      for (int r = 0; r < 4; ++r) {
        const long grow = crow0 + tm * 16 + quad * 4 + r;
        const long idx = cBase + grow * (long)Nn + gcol;
        const float val = acc[tm][tn][r] + bv;
        if (OUTSPLIT) {
          unsigned short h = f2bf(val);
          Ch[idx] = h;
          Cl[idx] = f2bf(val - bf2f(h));
        } else {
          Cp[idx] = val;
        }
      }
    }
  }
}

// ---------------- P3+P4a fused: row stats & column partial stats -------------
__global__ void k_rcstats(const float* __restrict__ S, float* __restrict__ m1,
                          float* __restrict__ r1, float* __restrict__ mp,
                          float* __restrict__ sp) {
  if (blockIdx.x < 4096) {
    // per-row (over k) max & 1/sumexp; one wave per row
    const int lane = threadIdx.x & 63;
    const int wave = threadIdx.x >> 6;
    const long row = (long)blockIdx.x * 4 + wave;
    const f32x4* p = (const f32x4*)(S + (row << 10));
    f32x4 v[4];
#pragma unroll
    for (int j = 0; j < 4; ++j) v[j] = p[lane + j * 64];
    float mx = -3.4e38f;
#pragma unroll
    for (int j = 0; j < 4; ++j)
#pragma unroll
      for (int c = 0; c < 4; ++c) mx = fmaxf(mx, v[j][c]);
#pragma unroll
    for (int off = 32; off > 0; off >>= 1) mx = fmaxf(mx, __shfl_xor(mx, off, 64));
    float s = 0.0f;
#pragma unroll
    for (int j = 0; j < 4; ++j)
#pragma unroll
      for (int c = 0; c < 4; ++c) s += __expf(v[j][c] - mx);
#pragma unroll
    for (int off = 32; off > 0; off >>= 1) s += __shfl_xor(s, off, 64);
    if (lane == 0) { m1[row] = mx; r1[row] = 1.0f / s; }
  } else {
    // per-column (over l) partial stats, 256-row strips
    const int b = blockIdx.x - 4096;
    const int kc = b & 3, lc = (b >> 2) & 3, n = b >> 4;
    const int k = kc * 256 + threadIdx.x;
    const float* p = S + ((long)n << 20) + ((long)(lc * 256) << 10) + k;
    float m = -3.4e38f, s = 0.0f;
    for (int i = 0; i < 256; ++i) {
      const float x = p[(long)i << 10];
      const float nm = fmaxf(m, x);
      s = s * __expf(m - nm) + __expf(x - nm);
      m = nm;
    }
    const long o = ((long)(n * 4 + lc) << 10) + k;
    mp[o] = m; sp[o] = s;
  }
}

__global__ void k_colstats_comb(const float* __restrict__ mp, const float* __restrict__ sp,
                                float* __restrict__ m2, float* __restrict__ r2) {
  const int n = blockIdx.y;
  const int k = blockIdx.x * 256 + threadIdx.x;
  float m = -3.4e38f, s = 0.0f;
#pragma unroll
  for (int c = 0; c < 4; ++c) {
    const long o = ((long)(n * 4 + c) << 10) + k;
    const float mc = mp[o], sc = sp[o];
    const float nm = fmaxf(m, mc);
    s = s * __expf(m - nm) + sc * __expf(mc - nm);
    m = nm;
  }
  m2[((long)n << 10) + k] = m;
  r2[((long)n << 10) + k] = 1.0f / s;
}

// ---------------- P5: A1 = softmax_k(S) bf16 ; A2T = softmax_l(S)^T bf16 -----
__global__ void k_agen(const float* __restrict__ S, const float* __restrict__ m1,
                       const float* __restrict__ r1, const float* __restrict__ m2,
                       const float* __restrict__ r2, unsigned short* __restrict__ A1,
                       unsigned short* __restrict__ A2T) {
  __shared__ float e2[64][65];
  const int n = blockIdx.z;
  const int k0 = blockIdx.x * 64, l0 = blockIdx.y * 64;
  const int q = threadIdx.x >> 4, p = threadIdx.x & 15;
  const long nb = (long)n << 20;
  const int kk = k0 + p * 4;
  const f32x4 mm2 = *(const f32x4*)(m2 + ((long)n << 10) + kk);
  const f32x4 rr2 = *(const f32x4*)(r2 + ((long)n << 10) + kk);
#pragma unroll
  for (int rr = 0; rr < 4; ++rr) {
    const int lrow = rr * 16 + q;
    const int l = l0 + lrow;
    const f32x4 s4 = *(const f32x4*)(S + nb + ((long)l << 10) + kk);
    const float mv = m1[((long)n << 10) + l], rv = r1[((long)n << 10) + l];
    u16x4 o;
#pragma unroll
    for (int j = 0; j < 4; ++j) {
      o[j] = f2bf(__expf(s4[j] - mv) * rv);
      e2[lrow][p * 4 + j] = __expf(s4[j] - mm2[j]) * rr2[j];
    }
    *(u16x4*)(A1 + nb + ((long)l << 10) + kk) = o;
  }
  __syncthreads();
#pragma unroll
  for (int rr = 0; rr < 4; ++rr) {
    const int krow = rr * 16 + q;
    u16x4 o;
#pragma unroll
    for (int j = 0; j < 4; ++j) o[j] = f2bf(e2[p * 4 + j][krow]);
    *(u16x4*)(A2T + nb + ((long)(k0 + krow) << 10) + (l0 + p * 4)) = o;
  }
}

// ---------------- transpose fp32 [n][r][c] -> bf16 [n][c][r], both inputs ----
__global__ void k_transpose2(const float* __restrict__ in0, unsigned short* __restrict__ out0,
                             const float* __restrict__ in1, unsigned short* __restrict__ out1) {
  __shared__ float t[64][65];
  const int zz = blockIdx.z;
  const int n = zz & 15;
  const float* in = (zz < 16) ? in0 : in1;
  unsigned short* out = (zz < 16) ? out0 : out1;
  const int c0 = blockIdx.x * 64, r0 = blockIdx.y * 64;
  const int q = threadIdx.x >> 4, p = threadIdx.x & 15;
  const long nb = (long)n << 20;
#pragma unroll
  for (int rr = 0; rr < 4; ++rr) {
    const int r = rr * 16 + q;
    const f32x4 v = *(const f32x4*)(in + nb + ((long)(r0 + r) << 10) + c0 + p * 4);
#pragma unroll
    for (int j = 0; j < 4; ++j) t[r][p * 4 + j] = v[j];
  }
  __syncthreads();
#pragma unroll
  for (int rr = 0; rr < 4; ++rr) {
    const int c = rr * 16 + q;
    u16x4 o;
#pragma unroll
    for (int j = 0; j < 4; ++j) o[j] = f2bf(t[p * 4 + j][c]);
    *(u16x4*)(out + nb + ((long)(c0 + c) << 10) + (r0 + p * 4)) = o;
  }
}

extern "C" void kernel_launch(void* const* d_in, const int* in_sizes, int n_in,
                              void* d_out, int out_size, void* d_ws, size_t ws_size,
                              hipStream_t stream) {
  const float* a1 = (const float*)d_in[0];
  const float* a2 = (const float*)d_in[1];
  const float* Gw = (const float*)d_in[2];
  const float* Gb = (const float*)d_in[3];
  float* out = (float*)d_out;
  char* ws = (char*)d_ws;
  const size_t MB = 1ull << 20;

  // phase-1 regions
  unsigned short* a1h  = (unsigned short*)(ws + 0 * MB);
  unsigned short* a1l  = (unsigned short*)(ws + 32 * MB);
  unsigned short* a2h  = (unsigned short*)(ws + 64 * MB);
  unsigned short* a2l  = (unsigned short*)(ws + 96 * MB);
  unsigned short* a2ph = (unsigned short*)(ws + 128 * MB);
  unsigned short* a2pl = (unsigned short*)(ws + 160 * MB);
  unsigned short* Gh   = (unsigned short*)(ws + 192 * MB);
  unsigned short* Gl   = (unsigned short*)(ws + 194 * MB);
  char* st = ws + 196 * MB;
  float* m1 = (float*)(st);
  float* r1 = (float*)(st + 64 * 1024);
  float* m2 = (float*)(st + 128 * 1024);
  float* r2 = (float*)(st + 192 * 1024);
  float* mp = (float*)(st + 256 * 1024);
  float* sp = (float*)(st + 512 * 1024);
  // lifetime-reused regions
  float* S            = (float*)(ws + 64 * MB);           // over a2h/a2l (dead after P1)
  unsigned short* A1  = (unsigned short*)(ws + 0 * MB);   // over a1h (dead after P2)
  unsigned short* A2T = (unsigned short*)(ws + 32 * MB);  // over a1l
  unsigned short* a2T = (unsigned short*)(ws + 128 * MB); // over a2ph (dead after P2)
  unsigned short* a1T = (unsigned short*)(ws + 160 * MB); // over a2pl

  const long B1M = 1048576;

  // P0: hi/lo splits (a1 & a2 fused; G separate)
  k_split2<<<dim3(16384, 2), 256, 0, stream>>>(a1, a1h, a1l, a2, a2h, a2l);
  k_split<<<1024, 256, 0, stream>>>(Gw, Gh, Gl, 262144);

  // P1: a2p[m][e] = a2[m][:] . Gw[e][:] + Gb[e]   (M=16384 -> 64x4 tiles)
  k_gemm256<true, true, false><<<256, 512, 0, stream>>>(
      a2h, a2l, Gh, Gl, Gb, nullptr, a2ph, a2pl, nullptr, nullptr, nullptr,
      1024, 1024, 0, 0, 0, 6, 2);

  // P2: S[n][l][k] = a1[n][l][:] . a2p[n][k][:]   (fp32 out, 4x4x16 tiles)
  k_gemm256<true, false, false><<<256, 512, 0, stream>>>(
      a1h, a1l, a2ph, a2pl, nullptr, S, nullptr, nullptr, nullptr, nullptr, nullptr,
      1024, 1024, B1M, B1M, B1M, 2, 2);

  // P3+P4a fused: row stats + col partial stats (one S read each)
  k_rcstats<<<4352, 256, 0, stream>>>(S, m1, r1, mp, sp);
  k_colstats_comb<<<dim3(4, 16), 256, 0, stream>>>(mp, sp, m2, r2);

  // P5: A1 (softmax over k) and A2T (softmax over l, transposed) in bf16
  k_agen<<<dim3(16, 16, 16), 256, 0, stream>>>(S, m1, r1, m2, r2, A1, A2T);

  // bf16 transposes of the raw inputs (both in one launch)
  k_transpose2<<<dim3(16, 16, 32), 256, 0, stream>>>(a2, a2T, a1, a1T);

  // P6+P7 merged: z<16 -> M1 = A1 . a2T^T ; z>=16 -> M2 = A2T . a1T^T
  k_gemm256<false, false, true><<<512, 512, 0, stream>>>(
      A1, nullptr, a2T, nullptr, nullptr, out, nullptr, nullptr,
      A2T, a1T, out + 16777216,
      1024, 1024, B1M, B1M, B1M, 2, 2);
}